// Round 9
// baseline (268.739 us; speedup 1.0000x reference)
//
#include <hip/hip_runtime.h>
#include <cstdint>
#include <cstddef>

// ---------- common ----------
typedef __bf16 bf16x8 __attribute__((ext_vector_type(8)));
typedef float  f32x4  __attribute__((ext_vector_type(4)));
typedef unsigned short u16x8 __attribute__((ext_vector_type(8)));

__device__ __forceinline__ uint16_t f2bf(float f) {
  uint32_t u = __float_as_uint(f);
  u += 0x7fffu + ((u >> 16) & 1u);          // round-to-nearest-even
  return (uint16_t)(u >> 16);
}
__device__ __forceinline__ float bf2f(uint16_t u) {
  return __uint_as_float((uint32_t)u << 16);
}
// packed f32x2 -> bf16x2 (dst.lo=lo, dst.hi=hi), RTNE in HW
__device__ __forceinline__ uint32_t cvtpk(float lo, float hi) {
  uint32_t r;
  asm("v_cvt_pk_bf16_f32 %0, %1, %2" : "=v"(r) : "v"(lo), "v"(hi));
  return r;
}

__device__ __forceinline__ f32x4 mfma16(bf16x8 a, bf16x8 b, f32x4 c) {
  return __builtin_amdgcn_mfma_f32_16x16x32_bf16(a, b, c, 0, 0, 0);
}

#define GLD_TO_LDS16(gptr, lptr)                                                   \
  __builtin_amdgcn_global_load_lds(                                                \
      (const __attribute__((address_space(1))) void*)(gptr),                       \
      (__attribute__((address_space(3))) void*)(lptr), 16, 0, 0)

// ---------- prep: fused fp32->bf16 cast of 4 tensors + hard bitpack ----------
__global__ void prep(const float* __restrict__ q, const float* __restrict__ k,
                     const float* __restrict__ w, const float* __restrict__ wo,
                     const float* __restrict__ hard,
                     uint16_t* __restrict__ Xq, uint16_t* __restrict__ Xk,
                     uint16_t* __restrict__ Wb, uint16_t* __restrict__ Wob,
                     uint32_t* __restrict__ bits) {
  const int bid = blockIdx.x;
  if (bid < 12288) {
    int i = bid * 256 + threadIdx.x;
    const float* src;
    uint16_t* dst;
    int off;
    if (i < 1048576)      { src = q;  dst = Xq;  off = i; }
    else if (i < 2097152) { src = k;  dst = Xk;  off = i - 1048576; }
    else if (i < 2883584) { src = w;  dst = Wb;  off = i - 2097152; }
    else                  { src = wo; dst = Wob; off = i - 2883584; }
    float4 v = ((const float4*)src)[off];
    ushort4 o;
    o.x = f2bf(v.x); o.y = f2bf(v.y); o.z = f2bf(v.z); o.w = f2bf(v.w);
    ((ushort4*)dst)[off] = o;
  } else {
    int base = (bid - 12288) * 1024;
#pragma unroll
    for (int c = 0; c < 4; c++) {
      int i = base + c * 256 + threadIdx.x;
      unsigned long long m = __ballot(hard[i] != 0.0f);
      if ((threadIdx.x & 63) == 0) {
        int wd = i >> 5;
        bits[wd]     = (uint32_t)m;
        bits[wd + 1] = (uint32_t)(m >> 32);
      }
    }
  }
}

// ---------- fused Q + KV projection, 128x128 tiles, BK=64, grid 768 ----------
// Frozen at R12 structure (51.9-53.5 us): single-buffer 2-phase, BK=64,
// both-sides XOR swizzle (conflicts 0), XCD-bijective block swizzle
// (FETCH 24 MB). 8-phase ports and dbuf both regressed (R9/R10/R13).
__global__ __launch_bounds__(256)
void gemm_qkv(const uint16_t* __restrict__ Xq, const uint16_t* __restrict__ Xk,
              const uint16_t* __restrict__ Wb, const float* __restrict__ ipb,
              uint16_t* __restrict__ Qb, uint16_t* __restrict__ Kb,
              uint16_t* __restrict__ Vt) {
  __shared__ __align__(16) char As[128 * 128];   // 16 KB: 128 rows x 128B (swz)
  __shared__ __align__(16) char Bs[128 * 128];   // 16 KB
  const int tid  = threadIdx.x;
  const int wave = tid >> 6, lane = tid & 63;
  const int quad = lane >> 4, l16 = lane & 15;
  const int sw = (l16 & 7) << 4;                 // read-side XOR swizzle

  const int swz = (blockIdx.x & 7) * 96 + (blockIdx.x >> 3);  // XCD-bijective
  const uint16_t *A, *B;
  const float* bias;
  int bm, bn, mode;
  if (swz < 256) {
    mode = 0; A = Xq; B = Wb; bias = ipb;
    bm = swz >> 3; bn = swz & 7;
  } else {
    mode = 1; A = Xk; B = Wb + (1 << 20); bias = ipb + 1024;
    int t = swz - 256; bm = t >> 4; bn = t & 15;
  }
  const int wm = (wave >> 1) << 6, wn = (wave & 1) << 6;

  // staging: 8 lanes per 128B row; pre-swizzled source column
  const int lrow = lane >> 3;
  const int scol = ((lane & 7) ^ lrow) << 4;
  const char* Ag = (const char*)A + (size_t)(bm * 128) * 2048;
  const char* Bg = (const char*)B + (size_t)(bn * 128) * 2048;

  f32x4 acc[4][4] = {};

  for (int k0 = 0; k0 < 2048; k0 += 128) {   // k0 in BYTES (BK=64 elems)
    __syncthreads();
#pragma unroll
    for (int j = 0; j < 4; j++) {
      const int rbase = j * 32 + wave * 8;
      GLD_TO_LDS16(Ag + (size_t)(rbase + lrow) * 2048 + k0 + scol,
                   As + rbase * 128);
      GLD_TO_LDS16(Bg + (size_t)(rbase + lrow) * 2048 + k0 + scol,
                   Bs + rbase * 128);
    }
    __syncthreads();

    bf16x8 af[4][2], bfr[4][2];
#pragma unroll
    for (int i = 0; i < 4; i++) {
      const char* pa = As + (wm + i * 16 + l16) * 128;
      const char* pb = Bs + (wn + i * 16 + l16) * 128;
#pragma unroll
      for (int ks = 0; ks < 2; ks++) {
        af[i][ks]  = *(const bf16x8*)(pa + ((ks * 64 + quad * 16) ^ sw));
        bfr[i][ks] = *(const bf16x8*)(pb + ((ks * 64 + quad * 16) ^ sw));
      }
    }
#pragma unroll
    for (int ks = 0; ks < 2; ks++)
#pragma unroll
      for (int mi = 0; mi < 4; mi++)
#pragma unroll
        for (int ni = 0; ni < 4; ni++)
          acc[mi][ni] = mfma16(af[mi][ks], bfr[ni][ks], acc[mi][ni]);
  }

#pragma unroll
  for (int mi = 0; mi < 4; mi++)
#pragma unroll
    for (int ni = 0; ni < 4; ni++)
#pragma unroll
      for (int r = 0; r < 4; r++) {
        int gi = bm * 128 + wm + mi * 16 + quad * 4 + r;  // row = t*4+b
        int gf = bn * 128 + wn + ni * 16 + l16;
        float c = acc[mi][ni][r] + bias[gf];
        if (mode == 0) {
          c *= 0.125f;  // HD^-0.5
          int t = gi >> 2, b = gi & 3, h = gf >> 6, d = gf & 63;
          Qb[((((size_t)b * 16 + h) * 1024 + t) << 6) + d] = f2bf(c);
        } else {
          int s = gi >> 2, b = gi & 3;
          if (gf < 1024) {
            int h = gf >> 6, d = gf & 63;
            Kb[((((size_t)b * 16 + h) * 1024 + s) << 6) + d] = f2bf(c);
          } else {
            int fv = gf - 1024, h = fv >> 6, d = fv & 63;
            Vt[((((size_t)b * 16 + h) * 64 + d) << 10) + s] = f2bf(c);
          }
        }
      }
}

// ---------- attention: swapped QK/PV, K staged, V direct from L2 ----------
// R15: dropped Vs staging (Common-mistake #7 / m169: V per XCD ~1 MB,
// L2-resident). V frags read direct: 16 rows x 64B segments, issued right
// after the K barrier so the QK phase (~600 cyc) covers L2 latency.
// LDS 64 -> 48 KB => 3 blocks/CU (was 2); staging traffic halved.
__global__ __launch_bounds__(256, 3)
void attn_kernel(const uint16_t* __restrict__ qb, const uint16_t* __restrict__ kb,
                 const uint16_t* __restrict__ vtb, const uint32_t* __restrict__ bits,
                 uint16_t* __restrict__ attn_out, float* __restrict__ rlout) {
  __shared__ __align__(16) uint16_t Ks[128 * 64];    // [s][d] swizzled, 16 KB
  __shared__ __align__(16) uint16_t Pb[4 * 32 * 128];// per-wave [t32][s128], 32 KB

  const int bid = blockIdx.x;              // 512 blocks
  const int xcd = bid & 7, j = bid >> 3;   // round-robin dispatch -> XCD
  const int slab = xcd * 8 + (j >> 3);     // 8 (b,h) slabs per XCD
  const int b = slab >> 4, h = slab & 15;
  const int t0 = (j & 7) << 7;             // 128 t-rows per block
  const int tid = threadIdx.x, wave = tid >> 6, lane = tid & 63;
  const int quad = lane >> 4, l16 = lane & 15;
  const int sw = (l16 & 7) << 4;           // XOR swizzle for row=l16 reads
  const size_t bh = (size_t)b * 16 + h;
  const int tw = t0 + wave * 32;
  const int ta = tw + l16, tb = ta + 16;   // lane's two t rows
  char* PwA = (char*)(Pb + wave * (32 * 128)) + l16 * 256;
  char* PwB = PwA + 16 * 256;

  // Q B-frags (op1: col=t=l16), rows ta / tb
  const uint16_t* qA = qb + ((bh << 10) + ta) * 64;
  bf16x8 aqA0 = *(const bf16x8*)(qA + quad * 8);
  bf16x8 aqA1 = *(const bf16x8*)(qA + 32 + quad * 8);
  bf16x8 aqB0 = *(const bf16x8*)(qA + 1024 + quad * 8);
  bf16x8 aqB1 = *(const bf16x8*)(qA + 1024 + 32 + quad * 8);

  f32x4 accA[4] = {}, accB[4] = {};
  float smA = 0.f, smB = 0.f;

  const int kr = tid >> 3, kc8 = tid & 7;    // K staging: 32 rows/round

  const uint32_t* bA = bits + (((size_t)(b << 10) + ta) << 5);
  const uint32_t* bB = bits + (((size_t)(b << 10) + tb) << 5);

  // V direct-read base for this lane's d-rows (d = dt*16+l16)
  const uint16_t* vbase = vtb + ((bh << 6) + l16) * 1024 + quad * 8;

  // prologue: coalesced K loads of chunk 0 + its mask words
  u16x8 kreg[4];
#pragma unroll
  for (int r = 0; r < 4; r++)
    kreg[r] = *(const u16x8*)(kb + (bh << 16) + (size_t)(r * 256 + tid) * 8);
  uint4 uA = *(const uint4*)bA;
  uint4 uB = *(const uint4*)bB;

  for (int sc = 0; sc < 8; sc++) {
    // pre-shifted mask words for this chunk (from prefetched uA/uB)
    uint32_t wA[4] = {uA.x >> (quad * 4), uA.y >> (quad * 4),
                      uA.z >> (quad * 4), uA.w >> (quad * 4)};
    uint32_t wB[4] = {uB.x >> (quad * 4), uB.y >> (quad * 4),
                      uB.z >> (quad * 4), uB.w >> (quad * 4)};

    __syncthreads();  // prior chunk's Ks reads done; staging loads drained
#pragma unroll
    for (int r = 0; r < 4; r++) {
      const int row = r * 32 + kr;
      *(u16x8*)((char*)Ks + row * 128 + ((kc8 * 16) ^ ((row & 7) << 4))) = kreg[r];
    }
    __syncthreads();  // staging visible

    // V frags for THIS chunk, direct from global (L2); QK phase covers latency
    bf16x8 vf[4][4];
#pragma unroll
    for (int kc = 0; kc < 4; kc++)
#pragma unroll
      for (int dt = 0; dt < 4; dt++)
        vf[kc][dt] = *(const bf16x8*)(vbase + (dt << 14) + sc * 128 + kc * 32);

    if (sc < 7) {  // T14: next chunk's K + masks; latency hides under compute
      const uint16_t* kbase = kb + (bh << 16) + (size_t)(sc + 1) * 8192;
#pragma unroll
      for (int r = 0; r < 4; r++)
        kreg[r] = *(const u16x8*)(kbase + (size_t)(r * 256 + tid) * 8);
      uA = *(const uint4*)(bA + (sc + 1) * 4);
      uB = *(const uint4*)(bB + (sc + 1) * 4);
    }

    // QK^T (swapped: D[s=quad*4+r][t=l16]) + streamed exp -> packed P rows
#pragma unroll
    for (int nn = 0; nn < 8; nn++) {
      const char* kbp = (const char*)Ks + (nn * 16 + l16) * 128;
      bf16x8 bk0 = *(const bf16x8*)(kbp + ((quad * 16) ^ sw));
      bf16x8 bk1 = *(const bf16x8*)(kbp + ((64 + quad * 16) ^ sw));
      f32x4 cA = {}, cB = {};
      cA = mfma16(bk0, aqA0, cA); cA = mfma16(bk1, aqA1, cA);
      cB = mfma16(bk0, aqB0, cB); cB = mfma16(bk1, aqB1, cB);
      const uint32_t mA = wA[nn >> 1] >> ((nn & 1) * 16);
      const uint32_t mB = wB[nn >> 1] >> ((nn & 1) * 16);
      float eA[4], eB[4];
#pragma unroll
      for (int r = 0; r < 4; r++) {
        eA[r] = __expf(cA[r]); smA += eA[r];
        eB[r] = __expf(cB[r]); smB += eB[r];
        eA[r] = ((mA >> r) & 1) ? eA[r] : 0.f;  // mask AFTER rowsum (softmax*hard)
        eB[r] = ((mB >> r) & 1) ? eB[r] : 0.f;
      }
      const int pc = (nn * 32 + quad * 8) ^ sw;
      *(uint2*)(PwA + pc) = make_uint2(cvtpk(eA[0], eA[1]), cvtpk(eA[2], eA[3]));
      *(uint2*)(PwB + pc) = make_uint2(cvtpk(eB[0], eB[1]), cvtpk(eB[2], eB[3]));
    }

    // PV (swapped: D[d=quad*4+r][t=l16]); P wave-private -> no barrier
#pragma unroll
    for (int kc = 0; kc < 4; kc++) {
      const int pcb = (kc * 64 + quad * 16) ^ sw;
      bf16x8 apA = *(const bf16x8*)(PwA + pcb);
      bf16x8 apB = *(const bf16x8*)(PwB + pcb);
#pragma unroll
      for (int dt = 0; dt < 4; dt++) {
        accA[dt] = mfma16(vf[kc][dt], apA, accA[dt]);
        accB[dt] = mfma16(vf[kc][dt], apB, accB[dt]);
      }
    }
  }

  // row-sums: t is lane-local; reduce across quads only
  smA += __shfl_xor(smA, 16); smA += __shfl_xor(smA, 32);
  smB += __shfl_xor(smB, 16); smB += __shfl_xor(smB, 32);
  const float rlA = 1.0f / smA, rlB = 1.0f / smB;
  if (quad == 0) rlout[(bh << 10) + ta] = rlA;
  if (quad == 1) rlout[(bh << 10) + tb] = rlB;

  // O epilogue: 4 consecutive d per lane -> packed 8B stores
#pragma unroll
  for (int dt = 0; dt < 4; dt++) {
    uint2 oA = make_uint2(cvtpk(accA[dt][0] * rlA, accA[dt][1] * rlA),
                          cvtpk(accA[dt][2] * rlA, accA[dt][3] * rlA));
    *(uint2*)(attn_out + ((size_t)(ta * 4 + b) << 10) + h * 64 + dt * 16 + quad * 4) = oA;
    uint2 oB = make_uint2(cvtpk(accB[dt][0] * rlB, accB[dt][1] * rlB),
                          cvtpk(accB[dt][2] * rlB, accB[dt][3] * rlB));
    *(uint2*)(attn_out + ((size_t)(tb * 4 + b) << 10) + h * 64 + dt * 16 + quad * 4) = oB;
  }
}

// ---------- tail: fused avg (blocks 0..511) + out-projection (512..1023) ----
// R15: avg stages 2 heads per barrier pair (Ks[2], 32 KB) -> 16 barriers
// per block instead of 32; T14 prefetch of the next head-pair kept.
__global__ __launch_bounds__(256, 4)
void tail(const uint16_t* __restrict__ qb, const uint16_t* __restrict__ kb,
          const float* __restrict__ rlin, const float* __restrict__ hard,
          const uint16_t* __restrict__ Ao, const uint16_t* __restrict__ Bw,
          const float* __restrict__ opb,
          float* __restrict__ out, float* __restrict__ avgout) {
  __shared__ __align__(16) char smem[32768];
  const int bid = blockIdx.x;
  const int tid = threadIdx.x, wave = tid >> 6, lane = tid & 63;
  const int quad = lane >> 4, l16 = lane & 15;

  if (bid < 512) {
    // ---- avg path: swapped-operand QK, 2-head swizzled K staging ----
    const int xcd = bid & 7, j = bid >> 3;   // j in [0,64)
    const int slab = xcd * 4 + (j >> 4);     // [0,32): 4 (b,s0) slabs per XCD
    const int b  = slab >> 3;
    const int s0 = (slab & 7) << 7;
    const int t0 = (j & 15) << 6;
    const int sw = (l16 & 7) << 4;
    const int tr = t0 + wave * 16 + l16;     // lane's t row
    const int krow = tid >> 3, kc8 = tid & 7;

    float av[8][4] = {};

    u16x8 krgA[4], krgB[4];
    auto loadK = [&](int hh, u16x8* krg) {
      const uint16_t* kb0 = kb + ((((size_t)b * 16 + hh) << 10) + s0) * 64;
#pragma unroll
      for (int r = 0; r < 4; r++)
        krg[r] = *(const u16x8*)(kb0 + (size_t)(r * 256 + tid) * 8);
    };
    loadK(0, krgA); loadK(1, krgB);

    for (int hp = 0; hp < 8; hp++) {
      __syncthreads();
#pragma unroll
      for (int r = 0; r < 4; r++) {
        const int row = r * 32 + krow;
        const int off = row * 128 + ((kc8 * 16) ^ ((row & 7) << 4));
        *(u16x8*)(smem + off) = krgA[r];
        *(u16x8*)(smem + 16384 + off) = krgB[r];
      }
      __syncthreads();
      if (hp < 7) { loadK(hp * 2 + 2, krgA); loadK(hp * 2 + 3, krgB); }

#pragma unroll
      for (int hs = 0; hs < 2; hs++) {
        const int hh = hp * 2 + hs;
        const char* Kbase = smem + hs * 16384;
        const size_t bh = (size_t)b * 16 + hh;
        const uint16_t* qrow = qb + ((bh << 10) + tr) * 64;
        bf16x8 aq0 = *(const bf16x8*)(qrow + quad * 8);
        bf16x8 aq1 = *(const bf16x8*)(qrow + 32 + quad * 8);
        const float rl = rlin[(bh << 10) + tr];

#pragma unroll
        for (int n = 0; n < 8; n++) {
          const char* kbp = Kbase + (n * 16 + l16) * 128;
          bf16x8 bk0 = *(const bf16x8*)(kbp + ((quad * 16) ^ sw));
          bf16x8 bk1 = *(const bf16x8*)(kbp + ((64 + quad * 16) ^ sw));
          f32x4 c = {};
          c = mfma16(bk0, aq0, c);
          c = mfma16(bk1, aq1, c);
#pragma unroll
          for (int r = 0; r < 4; r++) av[n][r] += __expf(c[r]) * rl;
        }
      }
    }

    // mask directly from immutable hard input (fp32 {0,1}), float4 per n
    const float* hrow = hard + (((size_t)(b << 10) + tr) << 10) + s0 + quad * 4;
    float* orow = avgout + ((size_t)(b << 10) + tr) * 1024 + s0 + quad * 4;
#pragma unroll
    for (int n = 0; n < 8; n++) {
      float4 hm = *(const float4*)(hrow + n * 16);
      float4 f;
      f.x = av[n][0] * (hm.x != 0.f ? 0.0625f : 0.f);
      f.y = av[n][1] * (hm.y != 0.f ? 0.0625f : 0.f);
      f.z = av[n][2] * (hm.z != 0.f ? 0.0625f : 0.f);
      f.w = av[n][3] * (hm.w != 0.f ? 0.0625f : 0.f);
      *(float4*)(orow + n * 16) = f;
    }
  } else {
    // ---- out-projection: 64x128 tiles, BK=64 + XOR swizzle ----
    char* As = smem;                 // 8 KB: 64 rows x 128B
    char* Bs = smem + 8192;          // 16 KB: 128 rows x 128B
    const int u = bid - 512;
    const int swz = (u & 7) * 64 + (u >> 3);   // same-bm blocks on one XCD
    const int bm = swz >> 3, bn = swz & 7;
    const int wm = (wave >> 1) << 5, wn = (wave & 1) << 6;
    const int sw = (l16 & 7) << 4;
    const int lrow = lane >> 3;
    const int scol = ((lane & 7) ^ lrow) << 4;
    const char* Ag = (const char*)Ao + (size_t)(bm * 64) * 2048;
    const char* Bg = (const char*)Bw + (size_t)(bn * 128) * 2048;

    f32x4 acc[2][4] = {};

    for (int k0 = 0; k0 < 2048; k0 += 128) {   // bytes; BK=64 elems
      __syncthreads();
#pragma unroll
      for (int jj = 0; jj < 2; jj++) {
        const int rbase = jj * 32 + wave * 8;
        GLD_TO_LDS16(Ag + (size_t)(rbase + lrow) * 2048 + k0 + scol,
                     As + rbase * 128);
      }
#pragma unroll
      for (int jj = 0; jj < 4; jj++) {
        const int rbase = jj * 32 + wave * 8;
        GLD_TO_LDS16(Bg + (size_t)(rbase + lrow) * 2048 + k0 + scol,
                     Bs + rbase * 128);
      }
      __syncthreads();

      bf16x8 af[2][2], bfr[4][2];
#pragma unroll
      for (int i = 0; i < 2; i++) {
        const char* pa = As + (wm + i * 16 + l16) * 128;
#pragma unroll
        for (int ks = 0; ks < 2; ks++)
          af[i][ks] = *(const bf16x8*)(pa + ((ks * 64 + quad * 16) ^ sw));
      }
#pragma unroll
      for (int i = 0; i < 4; i++) {
        const char* pb = Bs + (wn + i * 16 + l16) * 128;
#pragma unroll
        for (int ks = 0; ks < 2; ks++)
          bfr[i][ks] = *(const bf16x8*)(pb + ((ks * 64 + quad * 16) ^ sw));
      }
#pragma unroll
      for (int ks = 0; ks < 2; ks++)
#pragma unroll
        for (int mi = 0; mi < 2; mi++)
#pragma unroll
          for (int ni = 0; ni < 4; ni++)
            acc[mi][ni] = mfma16(af[mi][ks], bfr[ni][ks], acc[mi][ni]);
    }

#pragma unroll
    for (int mi = 0; mi < 2; mi++)
#pragma unroll
      for (int ni = 0; ni < 4; ni++)
#pragma unroll
        for (int r = 0; r < 4; r++) {
          int gi = bm * 64 + wm + mi * 16 + quad * 4 + r;
          int gf = bn * 128 + wn + ni * 16 + l16;
          out[(size_t)gi * 1024 + gf] = acc[mi][ni][r] + opb[gf];
        }
  }
}

// ---------- launch ----------
extern "C" void kernel_launch(void* const* d_in, const int* in_sizes, int n_in,
                              void* d_out, int out_size, void* d_ws, size_t ws_size,
                              hipStream_t stream) {
  const float* query = (const float*)d_in[0];
  const float* key   = (const float*)d_in[1];
  const float* hard  = (const float*)d_in[2];
  const float* ipw   = (const float*)d_in[3];
  const float* ipb   = (const float*)d_in[4];
  const float* opw   = (const float*)d_in[5];
  const float* opb   = (const float*)d_in[6];

  char* ws = (char*)d_ws;
  const size_t MB = 1ull << 20;
  uint16_t* Xq  = (uint16_t*)(ws + 0);        // 8 MB (reused as attn_out)
  uint16_t* Xk  = (uint16_t*)(ws + 8 * MB);   // 8 MB (reused as rl buffer)
  uint16_t* Wb  = (uint16_t*)(ws + 16 * MB);  // 6 MB
  uint16_t* Wob = (uint16_t*)(ws + 22 * MB);  // 2 MB
  uint16_t* Qb  = (uint16_t*)(ws + 24 * MB);  // 8 MB (b,h,t,d)
  uint16_t* Kb  = (uint16_t*)(ws + 32 * MB);  // 8 MB (b,h,s,d)
  uint16_t* Vt  = (uint16_t*)(ws + 40 * MB);  // 8 MB (b,h,d,s)
  uint16_t* AO  = Xq;                         // alias: Xq dead after gemm_qkv
  float*    rlws = (float*)(ws + 8 * MB);     // alias: Xk dead after gemm_qkv

  float* out = (float*)d_out;
  float* avg = out + 4194304;
  // bits (512 KB) parked in the out region: only read by attn, which
  // completes before tail's gemm_out path overwrites it.
  uint32_t* bits = (uint32_t*)out;

  // fused cast (12288 blocks) + bitpack (4096 blocks, 4x vectorized)
  prep<<<16384, 256, 0, stream>>>(query, key, ipw, opw, hard,
                                  Xq, Xk, Wb, Wob, bits);

  // fused Q-proj (256) + KV-proj (512), 128^2 BK=64 2-phase + swizzles
  gemm_qkv<<<768, 256, 0, stream>>>(Xq, Xk, Wb, ipb, Qb, Kb, Vt);

  // attention (K staged, V direct from L2, 3 blocks/CU): AO + 1/rowsum
  attn_kernel<<<512, 256, 0, stream>>>(Qb, Kb, Vt, bits, AO, rlws);

  // fused head-averaged attention map (2-head staging) + out-projection
  tail<<<1024, 256, 0, stream>>>(Qb, Kb, rlws, hard, AO, Wob, opb, out, avg);
}

// Round 10
// 244.658 us; speedup vs baseline: 1.0984x; 1.0984x over previous
//
#include <hip/hip_runtime.h>
#include <cstdint>
#include <cstddef>

// ---------- common ----------
typedef __bf16 bf16x8 __attribute__((ext_vector_type(8)));
typedef float  f32x4  __attribute__((ext_vector_type(4)));
typedef unsigned short u16x8 __attribute__((ext_vector_type(8)));

__device__ __forceinline__ uint16_t f2bf(float f) {
  uint32_t u = __float_as_uint(f);
  u += 0x7fffu + ((u >> 16) & 1u);          // round-to-nearest-even
  return (uint16_t)(u >> 16);
}
__device__ __forceinline__ float bf2f(uint16_t u) {
  return __uint_as_float((uint32_t)u << 16);
}
// packed f32x2 -> bf16x2 (dst.lo=lo, dst.hi=hi), RTNE in HW
__device__ __forceinline__ uint32_t cvtpk(float lo, float hi) {
  uint32_t r;
  asm("v_cvt_pk_bf16_f32 %0, %1, %2" : "=v"(r) : "v"(lo), "v"(hi));
  return r;
}

__device__ __forceinline__ f32x4 mfma16(bf16x8 a, bf16x8 b, f32x4 c) {
  return __builtin_amdgcn_mfma_f32_16x16x32_bf16(a, b, c, 0, 0, 0);
}

#define GLD_TO_LDS16(gptr, lptr)                                                   \
  __builtin_amdgcn_global_load_lds(                                                \
      (const __attribute__((address_space(1))) void*)(gptr),                       \
      (__attribute__((address_space(3))) void*)(lptr), 16, 0, 0)

// ---------- prep: fused fp32->bf16 cast of 4 tensors + hard bitpack ----------
__global__ void prep(const float* __restrict__ q, const float* __restrict__ k,
                     const float* __restrict__ w, const float* __restrict__ wo,
                     const float* __restrict__ hard,
                     uint16_t* __restrict__ Xq, uint16_t* __restrict__ Xk,
                     uint16_t* __restrict__ Wb, uint16_t* __restrict__ Wob,
                     uint32_t* __restrict__ bits) {
  const int bid = blockIdx.x;
  if (bid < 12288) {
    int i = bid * 256 + threadIdx.x;
    const float* src;
    uint16_t* dst;
    int off;
    if (i < 1048576)      { src = q;  dst = Xq;  off = i; }
    else if (i < 2097152) { src = k;  dst = Xk;  off = i - 1048576; }
    else if (i < 2883584) { src = w;  dst = Wb;  off = i - 2097152; }
    else                  { src = wo; dst = Wob; off = i - 2883584; }
    float4 v = ((const float4*)src)[off];
    ushort4 o;
    o.x = f2bf(v.x); o.y = f2bf(v.y); o.z = f2bf(v.z); o.w = f2bf(v.w);
    ((ushort4*)dst)[off] = o;
  } else {
    int base = (bid - 12288) * 1024;
#pragma unroll
    for (int c = 0; c < 4; c++) {
      int i = base + c * 256 + threadIdx.x;
      unsigned long long m = __ballot(hard[i] != 0.0f);
      if ((threadIdx.x & 63) == 0) {
        int wd = i >> 5;
        bits[wd]     = (uint32_t)m;
        bits[wd + 1] = (uint32_t)(m >> 32);
      }
    }
  }
}

// ---------- fused Q + KV projection, 128x128 tiles, BK=64, grid 768 ----------
// Frozen at R12 structure (51.9-53.5 us): single-buffer 2-phase, BK=64,
// both-sides XOR swizzle (conflicts 0), XCD-bijective block swizzle
// (FETCH 24 MB). 8-phase ports and dbuf both regressed (R9/R10/R13).
__global__ __launch_bounds__(256)
void gemm_qkv(const uint16_t* __restrict__ Xq, const uint16_t* __restrict__ Xk,
              const uint16_t* __restrict__ Wb, const float* __restrict__ ipb,
              uint16_t* __restrict__ Qb, uint16_t* __restrict__ Kb,
              uint16_t* __restrict__ Vt) {
  __shared__ __align__(16) char As[128 * 128];   // 16 KB: 128 rows x 128B (swz)
  __shared__ __align__(16) char Bs[128 * 128];   // 16 KB
  const int tid  = threadIdx.x;
  const int wave = tid >> 6, lane = tid & 63;
  const int quad = lane >> 4, l16 = lane & 15;
  const int sw = (l16 & 7) << 4;                 // read-side XOR swizzle

  const int swz = (blockIdx.x & 7) * 96 + (blockIdx.x >> 3);  // XCD-bijective
  const uint16_t *A, *B;
  const float* bias;
  int bm, bn, mode;
  if (swz < 256) {
    mode = 0; A = Xq; B = Wb; bias = ipb;
    bm = swz >> 3; bn = swz & 7;
  } else {
    mode = 1; A = Xk; B = Wb + (1 << 20); bias = ipb + 1024;
    int t = swz - 256; bm = t >> 4; bn = t & 15;
  }
  const int wm = (wave >> 1) << 6, wn = (wave & 1) << 6;

  // staging: 8 lanes per 128B row; pre-swizzled source column
  const int lrow = lane >> 3;
  const int scol = ((lane & 7) ^ lrow) << 4;
  const char* Ag = (const char*)A + (size_t)(bm * 128) * 2048;
  const char* Bg = (const char*)B + (size_t)(bn * 128) * 2048;

  f32x4 acc[4][4] = {};

  for (int k0 = 0; k0 < 2048; k0 += 128) {   // k0 in BYTES (BK=64 elems)
    __syncthreads();
#pragma unroll
    for (int j = 0; j < 4; j++) {
      const int rbase = j * 32 + wave * 8;
      GLD_TO_LDS16(Ag + (size_t)(rbase + lrow) * 2048 + k0 + scol,
                   As + rbase * 128);
      GLD_TO_LDS16(Bg + (size_t)(rbase + lrow) * 2048 + k0 + scol,
                   Bs + rbase * 128);
    }
    __syncthreads();

    bf16x8 af[4][2], bfr[4][2];
#pragma unroll
    for (int i = 0; i < 4; i++) {
      const char* pa = As + (wm + i * 16 + l16) * 128;
      const char* pb = Bs + (wn + i * 16 + l16) * 128;
#pragma unroll
      for (int ks = 0; ks < 2; ks++) {
        af[i][ks]  = *(const bf16x8*)(pa + ((ks * 64 + quad * 16) ^ sw));
        bfr[i][ks] = *(const bf16x8*)(pb + ((ks * 64 + quad * 16) ^ sw));
      }
    }
#pragma unroll
    for (int ks = 0; ks < 2; ks++)
#pragma unroll
      for (int mi = 0; mi < 4; mi++)
#pragma unroll
        for (int ni = 0; ni < 4; ni++)
          acc[mi][ni] = mfma16(af[mi][ks], bfr[ni][ks], acc[mi][ni]);
  }

#pragma unroll
  for (int mi = 0; mi < 4; mi++)
#pragma unroll
    for (int ni = 0; ni < 4; ni++)
#pragma unroll
      for (int r = 0; r < 4; r++) {
        int gi = bm * 128 + wm + mi * 16 + quad * 4 + r;  // row = t*4+b
        int gf = bn * 128 + wn + ni * 16 + l16;
        float c = acc[mi][ni][r] + bias[gf];
        if (mode == 0) {
          c *= 0.125f;  // HD^-0.5
          int t = gi >> 2, b = gi & 3, h = gf >> 6, d = gf & 63;
          Qb[((((size_t)b * 16 + h) * 1024 + t) << 6) + d] = f2bf(c);
        } else {
          int s = gi >> 2, b = gi & 3;
          if (gf < 1024) {
            int h = gf >> 6, d = gf & 63;
            Kb[((((size_t)b * 16 + h) * 1024 + s) << 6) + d] = f2bf(c);
          } else {
            int fv = gf - 1024, h = fv >> 6, d = fv & 63;
            Vt[((((size_t)b * 16 + h) * 64 + d) << 10) + s] = f2bf(c);
          }
        }
      }
}

// ---------- attention: swapped-operand QK/PV, XOR-swizzled LDS ----------
// R16: exact revert to the R6/R8 version (measured <=52 us). The R15
// V-direct experiment regressed to ~68 us: VGPR stayed 84 => the compiler
// SANK the V loads to the PV loop, exposing full L2 latency per chunk.
// Reg-staging V through LDS is what structurally forces the loads a full
// chunk early (the ds_write is a hard consumption point). Frozen.
__global__ __launch_bounds__(256, 2)
void attn_kernel(const uint16_t* __restrict__ qb, const uint16_t* __restrict__ kb,
                 const uint16_t* __restrict__ vtb, const uint32_t* __restrict__ bits,
                 uint16_t* __restrict__ attn_out, float* __restrict__ rlout) {
  __shared__ __align__(16) uint16_t Ks[128 * 64];    // [s][d] swizzled, 16 KB
  __shared__ __align__(16) uint16_t Vs[64 * 128];    // [d][s] swizzled, 16 KB
  __shared__ __align__(16) uint16_t Pb[4 * 32 * 128];// per-wave [t32][s128], 32 KB

  const int bid = blockIdx.x;              // 512 blocks
  const int xcd = bid & 7, j = bid >> 3;   // round-robin dispatch -> XCD
  const int slab = xcd * 8 + (j >> 3);     // 8 (b,h) slabs per XCD
  const int b = slab >> 4, h = slab & 15;
  const int t0 = (j & 7) << 7;             // 128 t-rows per block
  const int tid = threadIdx.x, wave = tid >> 6, lane = tid & 63;
  const int quad = lane >> 4, l16 = lane & 15;
  const int sw = (l16 & 7) << 4;           // XOR swizzle for row=l16 reads
  const size_t bh = (size_t)b * 16 + h;
  const int tw = t0 + wave * 32;
  const int ta = tw + l16, tb = ta + 16;   // lane's two t rows
  char* PwA = (char*)(Pb + wave * (32 * 128)) + l16 * 256;
  char* PwB = PwA + 16 * 256;

  // Q B-frags (op1: col=t=l16), rows ta / tb
  const uint16_t* qA = qb + ((bh << 10) + ta) * 64;
  bf16x8 aqA0 = *(const bf16x8*)(qA + quad * 8);
  bf16x8 aqA1 = *(const bf16x8*)(qA + 32 + quad * 8);
  bf16x8 aqB0 = *(const bf16x8*)(qA + 1024 + quad * 8);
  bf16x8 aqB1 = *(const bf16x8*)(qA + 1024 + 32 + quad * 8);

  f32x4 accA[4] = {}, accB[4] = {};
  float smA = 0.f, smB = 0.f;

  const int kr = tid >> 3, kc8 = tid & 7;    // K staging: 32 rows/round
  const int vr = tid >> 4, vc16 = tid & 15;  // V staging: 16 rows/round

  const uint32_t* bA = bits + (((size_t)(b << 10) + ta) << 5);
  const uint32_t* bB = bits + (((size_t)(b << 10) + tb) << 5);

  // prologue: coalesced loads of chunk 0 + its mask words
  u16x8 kreg[4], vreg[4];
#pragma unroll
  for (int r = 0; r < 4; r++)
    kreg[r] = *(const u16x8*)(kb + (bh << 16) + (size_t)(r * 256 + tid) * 8);
#pragma unroll
  for (int r = 0; r < 4; r++)
    vreg[r] = *(const u16x8*)(vtb + (((bh << 6) + r * 16 + vr) << 10) + vc16 * 8);
  uint4 uA = *(const uint4*)bA;
  uint4 uB = *(const uint4*)bB;

  for (int sc = 0; sc < 8; sc++) {
    // pre-shifted mask words for this chunk (from prefetched uA/uB)
    uint32_t wA[4] = {uA.x >> (quad * 4), uA.y >> (quad * 4),
                      uA.z >> (quad * 4), uA.w >> (quad * 4)};
    uint32_t wB[4] = {uB.x >> (quad * 4), uB.y >> (quad * 4),
                      uB.z >> (quad * 4), uB.w >> (quad * 4)};

    __syncthreads();  // prior chunk's LDS reads done; staging loads drained
#pragma unroll
    for (int r = 0; r < 4; r++) {
      const int row = r * 32 + kr;
      *(u16x8*)((char*)Ks + row * 128 + ((kc8 * 16) ^ ((row & 7) << 4))) = kreg[r];
    }
#pragma unroll
    for (int r = 0; r < 4; r++) {
      const int row = r * 16 + vr;
      *(u16x8*)((char*)Vs + row * 256 + ((vc16 * 16) ^ ((row & 7) << 4))) = vreg[r];
    }
    __syncthreads();  // staging visible

    if (sc < 7) {  // T14: issue next chunk's loads; latency hides under compute
      const uint16_t* kbase = kb + (bh << 16) + (size_t)(sc + 1) * 8192;
#pragma unroll
      for (int r = 0; r < 4; r++)
        kreg[r] = *(const u16x8*)(kbase + (size_t)(r * 256 + tid) * 8);
#pragma unroll
      for (int r = 0; r < 4; r++)
        vreg[r] = *(const u16x8*)(vtb + (((bh << 6) + r * 16 + vr) << 10) +
                                  (sc + 1) * 128 + vc16 * 8);
      uA = *(const uint4*)(bA + (sc + 1) * 4);
      uB = *(const uint4*)(bB + (sc + 1) * 4);
    }

    // QK^T (swapped: D[s=quad*4+r][t=l16]) + streamed exp -> packed P rows
#pragma unroll
    for (int nn = 0; nn < 8; nn++) {
      const char* kbp = (const char*)Ks + (nn * 16 + l16) * 128;
      bf16x8 bk0 = *(const bf16x8*)(kbp + ((quad * 16) ^ sw));
      bf16x8 bk1 = *(const bf16x8*)(kbp + ((64 + quad * 16) ^ sw));
      f32x4 cA = {}, cB = {};
      cA = mfma16(bk0, aqA0, cA); cA = mfma16(bk1, aqA1, cA);
      cB = mfma16(bk0, aqB0, cB); cB = mfma16(bk1, aqB1, cB);
      const uint32_t mA = wA[nn >> 1] >> ((nn & 1) * 16);
      const uint32_t mB = wB[nn >> 1] >> ((nn & 1) * 16);
      float eA[4], eB[4];
#pragma unroll
      for (int r = 0; r < 4; r++) {
        eA[r] = __expf(cA[r]); smA += eA[r];
        eB[r] = __expf(cB[r]); smB += eB[r];
        eA[r] = ((mA >> r) & 1) ? eA[r] : 0.f;  // mask AFTER rowsum (softmax*hard)
        eB[r] = ((mB >> r) & 1) ? eB[r] : 0.f;
      }
      const int pc = (nn * 32 + quad * 8) ^ sw;
      *(uint2*)(PwA + pc) = make_uint2(cvtpk(eA[0], eA[1]), cvtpk(eA[2], eA[3]));
      *(uint2*)(PwB + pc) = make_uint2(cvtpk(eB[0], eB[1]), cvtpk(eB[2], eB[3]));
    }

    // PV (swapped: D[d=quad*4+r][t=l16]); P wave-private -> no barrier
#pragma unroll
    for (int kc = 0; kc < 4; kc++) {
      const int pcb = (kc * 64 + quad * 16) ^ sw;
      bf16x8 apA = *(const bf16x8*)(PwA + pcb);
      bf16x8 apB = *(const bf16x8*)(PwB + pcb);
#pragma unroll
      for (int dt = 0; dt < 4; dt++) {
        bf16x8 bv = *(const bf16x8*)((const char*)Vs + (dt * 16 + l16) * 256 +
                                     ((kc * 64 + quad * 16) ^ sw));
        accA[dt] = mfma16(bv, apA, accA[dt]);
        accB[dt] = mfma16(bv, apB, accB[dt]);
      }
    }
  }

  // row-sums: t is lane-local; reduce across quads only
  smA += __shfl_xor(smA, 16); smA += __shfl_xor(smA, 32);
  smB += __shfl_xor(smB, 16); smB += __shfl_xor(smB, 32);
  const float rlA = 1.0f / smA, rlB = 1.0f / smB;
  if (quad == 0) rlout[(bh << 10) + ta] = rlA;
  if (quad == 1) rlout[(bh << 10) + tb] = rlB;

  // O epilogue: 4 consecutive d per lane -> packed 8B stores
#pragma unroll
  for (int dt = 0; dt < 4; dt++) {
    uint2 oA = make_uint2(cvtpk(accA[dt][0] * rlA, accA[dt][1] * rlA),
                          cvtpk(accA[dt][2] * rlA, accA[dt][3] * rlA));
    *(uint2*)(attn_out + ((size_t)(ta * 4 + b) << 10) + h * 64 + dt * 16 + quad * 4) = oA;
    uint2 oB = make_uint2(cvtpk(accB[dt][0] * rlB, accB[dt][1] * rlB),
                          cvtpk(accB[dt][2] * rlB, accB[dt][3] * rlB));
    *(uint2*)(attn_out + ((size_t)(tb * 4 + b) << 10) + h * 64 + dt * 16 + quad * 4) = oB;
  }
}

// ---------- tail: fused avg (blocks 0..511) + out-projection (512..1023) ----
// avg: 2-head swizzled K staging (16 barriers/block), XCD remap for K-reuse.
// out: 64x128 tiles, BK=64 + XOR swizzle.
__global__ __launch_bounds__(256, 4)
void tail(const uint16_t* __restrict__ qb, const uint16_t* __restrict__ kb,
          const float* __restrict__ rlin, const float* __restrict__ hard,
          const uint16_t* __restrict__ Ao, const uint16_t* __restrict__ Bw,
          const float* __restrict__ opb,
          float* __restrict__ out, float* __restrict__ avgout) {
  __shared__ __align__(16) char smem[32768];
  const int bid = blockIdx.x;
  const int tid = threadIdx.x, wave = tid >> 6, lane = tid & 63;
  const int quad = lane >> 4, l16 = lane & 15;

  if (bid < 512) {
    // ---- avg path: swapped-operand QK, 2-head swizzled K staging ----
    const int xcd = bid & 7, j = bid >> 3;   // j in [0,64)
    const int slab = xcd * 4 + (j >> 4);     // [0,32): 4 (b,s0) slabs per XCD
    const int b  = slab >> 3;
    const int s0 = (slab & 7) << 7;
    const int t0 = (j & 15) << 6;
    const int sw = (l16 & 7) << 4;
    const int tr = t0 + wave * 16 + l16;     // lane's t row
    const int krow = tid >> 3, kc8 = tid & 7;

    float av[8][4] = {};

    u16x8 krgA[4], krgB[4];
    auto loadK = [&](int hh, u16x8* krg) {
      const uint16_t* kb0 = kb + ((((size_t)b * 16 + hh) << 10) + s0) * 64;
#pragma unroll
      for (int r = 0; r < 4; r++)
        krg[r] = *(const u16x8*)(kb0 + (size_t)(r * 256 + tid) * 8);
    };
    loadK(0, krgA); loadK(1, krgB);

    for (int hp = 0; hp < 8; hp++) {
      __syncthreads();
#pragma unroll
      for (int r = 0; r < 4; r++) {
        const int row = r * 32 + krow;
        const int off = row * 128 + ((kc8 * 16) ^ ((row & 7) << 4));
        *(u16x8*)(smem + off) = krgA[r];
        *(u16x8*)(smem + 16384 + off) = krgB[r];
      }
      __syncthreads();
      if (hp < 7) { loadK(hp * 2 + 2, krgA); loadK(hp * 2 + 3, krgB); }

#pragma unroll
      for (int hs = 0; hs < 2; hs++) {
        const int hh = hp * 2 + hs;
        const char* Kbase = smem + hs * 16384;
        const size_t bh = (size_t)b * 16 + hh;
        const uint16_t* qrow = qb + ((bh << 10) + tr) * 64;
        bf16x8 aq0 = *(const bf16x8*)(qrow + quad * 8);
        bf16x8 aq1 = *(const bf16x8*)(qrow + 32 + quad * 8);
        const float rl = rlin[(bh << 10) + tr];

#pragma unroll
        for (int n = 0; n < 8; n++) {
          const char* kbp = Kbase + (n * 16 + l16) * 128;
          bf16x8 bk0 = *(const bf16x8*)(kbp + ((quad * 16) ^ sw));
          bf16x8 bk1 = *(const bf16x8*)(kbp + ((64 + quad * 16) ^ sw));
          f32x4 c = {};
          c = mfma16(bk0, aq0, c);
          c = mfma16(bk1, aq1, c);
#pragma unroll
          for (int r = 0; r < 4; r++) av[n][r] += __expf(c[r]) * rl;
        }
      }
    }

    // mask directly from immutable hard input (fp32 {0,1}), float4 per n
    const float* hrow = hard + (((size_t)(b << 10) + tr) << 10) + s0 + quad * 4;
    float* orow = avgout + ((size_t)(b << 10) + tr) * 1024 + s0 + quad * 4;
#pragma unroll
    for (int n = 0; n < 8; n++) {
      float4 hm = *(const float4*)(hrow + n * 16);
      float4 f;
      f.x = av[n][0] * (hm.x != 0.f ? 0.0625f : 0.f);
      f.y = av[n][1] * (hm.y != 0.f ? 0.0625f : 0.f);
      f.z = av[n][2] * (hm.z != 0.f ? 0.0625f : 0.f);
      f.w = av[n][3] * (hm.w != 0.f ? 0.0625f : 0.f);
      *(float4*)(orow + n * 16) = f;
    }
  } else {
    // ---- out-projection: 64x128 tiles, BK=64 + XOR swizzle ----
    char* As = smem;                 // 8 KB: 64 rows x 128B
    char* Bs = smem + 8192;          // 16 KB: 128 rows x 128B
    const int u = bid - 512;
    const int swz = (u & 7) * 64 + (u >> 3);   // same-bm blocks on one XCD
    const int bm = swz >> 3, bn = swz & 7;
    const int wm = (wave >> 1) << 5, wn = (wave & 1) << 6;
    const int sw = (l16 & 7) << 4;
    const int lrow = lane >> 3;
    const int scol = ((lane & 7) ^ lrow) << 4;
    const char* Ag = (const char*)Ao + (size_t)(bm * 64) * 2048;
    const char* Bg = (const char*)Bw + (size_t)(bn * 128) * 2048;

    f32x4 acc[2][4] = {};

    for (int k0 = 0; k0 < 2048; k0 += 128) {   // bytes; BK=64 elems
      __syncthreads();
#pragma unroll
      for (int jj = 0; jj < 2; jj++) {
        const int rbase = jj * 32 + wave * 8;
        GLD_TO_LDS16(Ag + (size_t)(rbase + lrow) * 2048 + k0 + scol,
                     As + rbase * 128);
      }
#pragma unroll
      for (int jj = 0; jj < 4; jj++) {
        const int rbase = jj * 32 + wave * 8;
        GLD_TO_LDS16(Bg + (size_t)(rbase + lrow) * 2048 + k0 + scol,
                     Bs + rbase * 128);
      }
      __syncthreads();

      bf16x8 af[2][2], bfr[4][2];
#pragma unroll
      for (int i = 0; i < 2; i++) {
        const char* pa = As + (wm + i * 16 + l16) * 128;
#pragma unroll
        for (int ks = 0; ks < 2; ks++)
          af[i][ks] = *(const bf16x8*)(pa + ((ks * 64 + quad * 16) ^ sw));
      }
#pragma unroll
      for (int i = 0; i < 4; i++) {
        const char* pb = Bs + (wn + i * 16 + l16) * 128;
#pragma unroll
        for (int ks = 0; ks < 2; ks++)
          bfr[i][ks] = *(const bf16x8*)(pb + ((ks * 64 + quad * 16) ^ sw));
      }
#pragma unroll
      for (int ks = 0; ks < 2; ks++)
#pragma unroll
        for (int mi = 0; mi < 2; mi++)
#pragma unroll
          for (int ni = 0; ni < 4; ni++)
            acc[mi][ni] = mfma16(af[mi][ks], bfr[ni][ks], acc[mi][ni]);
    }

#pragma unroll
    for (int mi = 0; mi < 2; mi++)
#pragma unroll
      for (int ni = 0; ni < 4; ni++)
#pragma unroll
        for (int r = 0; r < 4; r++) {
          int gi = bm * 64 + wm + mi * 16 + quad * 4 + r;
          int gf = bn * 128 + wn + ni * 16 + l16;
          out[(size_t)gi * 1024 + gf] = acc[mi][ni][r] + opb[gf];
        }
  }
}

// ---------- launch ----------
extern "C" void kernel_launch(void* const* d_in, const int* in_sizes, int n_in,
                              void* d_out, int out_size, void* d_ws, size_t ws_size,
                              hipStream_t stream) {
  const float* query = (const float*)d_in[0];
  const float* key   = (const float*)d_in[1];
  const float* hard  = (const float*)d_in[2];
  const float* ipw   = (const float*)d_in[3];
  const float* ipb   = (const float*)d_in[4];
  const float* opw   = (const float*)d_in[5];
  const float* opb   = (const float*)d_in[6];

  char* ws = (char*)d_ws;
  const size_t MB = 1ull << 20;
  uint16_t* Xq  = (uint16_t*)(ws + 0);        // 8 MB (reused as attn_out)
  uint16_t* Xk  = (uint16_t*)(ws + 8 * MB);   // 8 MB (reused as rl buffer)
  uint16_t* Wb  = (uint16_t*)(ws + 16 * MB);  // 6 MB
  uint16_t* Wob = (uint16_t*)(ws + 22 * MB);  // 2 MB
  uint16_t* Qb  = (uint16_t*)(ws + 24 * MB);  // 8 MB (b,h,t,d)
  uint16_t* Kb  = (uint16_t*)(ws + 32 * MB);  // 8 MB (b,h,s,d)
  uint16_t* Vt  = (uint16_t*)(ws + 40 * MB);  // 8 MB (b,h,d,s)
  uint16_t* AO  = Xq;                         // alias: Xq dead after gemm_qkv
  float*    rlws = (float*)(ws + 8 * MB);     // alias: Xk dead after gemm_qkv

  float* out = (float*)d_out;
  float* avg = out + 4194304;
  // bits (512 KB) parked in the out region: only read by attn, which
  // completes before tail's gemm_out path overwrites it.
  uint32_t* bits = (uint32_t*)out;

  // fused cast (12288 blocks) + bitpack (4096 blocks, 4x vectorized)
  prep<<<16384, 256, 0, stream>>>(query, key, ipw, opw, hard,
                                  Xq, Xk, Wb, Wob, bits);

  // fused Q-proj (256) + KV-proj (512), 128^2 BK=64 2-phase + swizzles
  gemm_qkv<<<768, 256, 0, stream>>>(Xq, Xk, Wb, ipb, Qb, Kb, Vt);

  // attention (K+V staged, swizzled, 2 blocks/CU): AO + 1/rowsum
  attn_kernel<<<512, 256, 0, stream>>>(Qb, Kb, Vt, bits, AO, rlws);

  // fused head-averaged attention map (2-head staging) + out-projection
  tail<<<1024, 256, 0, stream>>>(Qb, Kb, rlws, hard, AO, Wob, opb, out, avg);
}

// Round 11
// 228.140 us; speedup vs baseline: 1.1780x; 1.0724x over previous
//
#include <hip/hip_runtime.h>
#include <cstdint>
#include <cstddef>

// ---------- common ----------
typedef __bf16 bf16x8 __attribute__((ext_vector_type(8)));
typedef float  f32x4  __attribute__((ext_vector_type(4)));
typedef unsigned short u16x8 __attribute__((ext_vector_type(8)));

__device__ __forceinline__ uint16_t f2bf(float f) {
  uint32_t u = __float_as_uint(f);
  u += 0x7fffu + ((u >> 16) & 1u);          // round-to-nearest-even
  return (uint16_t)(u >> 16);
}
__device__ __forceinline__ float bf2f(uint16_t u) {
  return __uint_as_float((uint32_t)u << 16);
}
// packed f32x2 -> bf16x2 (dst.lo=lo, dst.hi=hi), RTNE in HW
__device__ __forceinline__ uint32_t cvtpk(float lo, float hi) {
  uint32_t r;
  asm("v_cvt_pk_bf16_f32 %0, %1, %2" : "=v"(r) : "v"(lo), "v"(hi));
  return r;
}

__device__ __forceinline__ f32x4 mfma16(bf16x8 a, bf16x8 b, f32x4 c) {
  return __builtin_amdgcn_mfma_f32_16x16x32_bf16(a, b, c, 0, 0, 0);
}

#define GLD_TO_LDS16(gptr, lptr)                                                   \
  __builtin_amdgcn_global_load_lds(                                                \
      (const __attribute__((address_space(1))) void*)(gptr),                       \
      (__attribute__((address_space(3))) void*)(lptr), 16, 0, 0)

// ---------- prep: fused fp32->bf16 cast of 4 tensors + hard bitpack ----------
__global__ void prep(const float* __restrict__ q, const float* __restrict__ k,
                     const float* __restrict__ w, const float* __restrict__ wo,
                     const float* __restrict__ hard,
                     uint16_t* __restrict__ Xq, uint16_t* __restrict__ Xk,
                     uint16_t* __restrict__ Wb, uint16_t* __restrict__ Wob,
                     uint32_t* __restrict__ bits) {
  const int bid = blockIdx.x;
  if (bid < 12288) {
    int i = bid * 256 + threadIdx.x;
    const float* src;
    uint16_t* dst;
    int off;
    if (i < 1048576)      { src = q;  dst = Xq;  off = i; }
    else if (i < 2097152) { src = k;  dst = Xk;  off = i - 1048576; }
    else if (i < 2883584) { src = w;  dst = Wb;  off = i - 2097152; }
    else                  { src = wo; dst = Wob; off = i - 2883584; }
    float4 v = ((const float4*)src)[off];
    ushort4 o;
    o.x = f2bf(v.x); o.y = f2bf(v.y); o.z = f2bf(v.z); o.w = f2bf(v.w);
    ((ushort4*)dst)[off] = o;
  } else {
    int base = (bid - 12288) * 1024;
#pragma unroll
    for (int c = 0; c < 4; c++) {
      int i = base + c * 256 + threadIdx.x;
      unsigned long long m = __ballot(hard[i] != 0.0f);
      if ((threadIdx.x & 63) == 0) {
        int wd = i >> 5;
        bits[wd]     = (uint32_t)m;
        bits[wd + 1] = (uint32_t)(m >> 32);
      }
    }
  }
}

// ---------- fused Q + KV projection, 128x128 tiles, BK=64, grid 768 ----------
// Frozen at R12 structure (51.9-53.5 us): single-buffer 2-phase, BK=64,
// both-sides XOR swizzle (conflicts 0), XCD-bijective block swizzle
// (FETCH 24 MB). 8-phase ports and dbuf both regressed (R9/R10/R13).
__global__ __launch_bounds__(256)
void gemm_qkv(const uint16_t* __restrict__ Xq, const uint16_t* __restrict__ Xk,
              const uint16_t* __restrict__ Wb, const float* __restrict__ ipb,
              uint16_t* __restrict__ Qb, uint16_t* __restrict__ Kb,
              uint16_t* __restrict__ Vt) {
  __shared__ __align__(16) char As[128 * 128];   // 16 KB: 128 rows x 128B (swz)
  __shared__ __align__(16) char Bs[128 * 128];   // 16 KB
  const int tid  = threadIdx.x;
  const int wave = tid >> 6, lane = tid & 63;
  const int quad = lane >> 4, l16 = lane & 15;
  const int sw = (l16 & 7) << 4;                 // read-side XOR swizzle

  const int swz = (blockIdx.x & 7) * 96 + (blockIdx.x >> 3);  // XCD-bijective
  const uint16_t *A, *B;
  const float* bias;
  int bm, bn, mode;
  if (swz < 256) {
    mode = 0; A = Xq; B = Wb; bias = ipb;
    bm = swz >> 3; bn = swz & 7;
  } else {
    mode = 1; A = Xk; B = Wb + (1 << 20); bias = ipb + 1024;
    int t = swz - 256; bm = t >> 4; bn = t & 15;
  }
  const int wm = (wave >> 1) << 6, wn = (wave & 1) << 6;

  // staging: 8 lanes per 128B row; pre-swizzled source column
  const int lrow = lane >> 3;
  const int scol = ((lane & 7) ^ lrow) << 4;
  const char* Ag = (const char*)A + (size_t)(bm * 128) * 2048;
  const char* Bg = (const char*)B + (size_t)(bn * 128) * 2048;

  f32x4 acc[4][4] = {};

  for (int k0 = 0; k0 < 2048; k0 += 128) {   // k0 in BYTES (BK=64 elems)
    __syncthreads();
#pragma unroll
    for (int j = 0; j < 4; j++) {
      const int rbase = j * 32 + wave * 8;
      GLD_TO_LDS16(Ag + (size_t)(rbase + lrow) * 2048 + k0 + scol,
                   As + rbase * 128);
      GLD_TO_LDS16(Bg + (size_t)(rbase + lrow) * 2048 + k0 + scol,
                   Bs + rbase * 128);
    }
    __syncthreads();

    bf16x8 af[4][2], bfr[4][2];
#pragma unroll
    for (int i = 0; i < 4; i++) {
      const char* pa = As + (wm + i * 16 + l16) * 128;
      const char* pb = Bs + (wn + i * 16 + l16) * 128;
#pragma unroll
      for (int ks = 0; ks < 2; ks++) {
        af[i][ks]  = *(const bf16x8*)(pa + ((ks * 64 + quad * 16) ^ sw));
        bfr[i][ks] = *(const bf16x8*)(pb + ((ks * 64 + quad * 16) ^ sw));
      }
    }
#pragma unroll
    for (int ks = 0; ks < 2; ks++)
#pragma unroll
      for (int mi = 0; mi < 4; mi++)
#pragma unroll
        for (int ni = 0; ni < 4; ni++)
          acc[mi][ni] = mfma16(af[mi][ks], bfr[ni][ks], acc[mi][ni]);
  }

#pragma unroll
  for (int mi = 0; mi < 4; mi++)
#pragma unroll
    for (int ni = 0; ni < 4; ni++)
#pragma unroll
      for (int r = 0; r < 4; r++) {
        int gi = bm * 128 + wm + mi * 16 + quad * 4 + r;  // row = t*4+b
        int gf = bn * 128 + wn + ni * 16 + l16;
        float c = acc[mi][ni][r] + bias[gf];
        if (mode == 0) {
          c *= 0.125f;  // HD^-0.5
          int t = gi >> 2, b = gi & 3, h = gf >> 6, d = gf & 63;
          Qb[((((size_t)b * 16 + h) * 1024 + t) << 6) + d] = f2bf(c);
        } else {
          int s = gi >> 2, b = gi & 3;
          if (gf < 1024) {
            int h = gf >> 6, d = gf & 63;
            Kb[((((size_t)b * 16 + h) * 1024 + s) << 6) + d] = f2bf(c);
          } else {
            int fv = gf - 1024, h = fv >> 6, d = fv & 63;
            Vt[((((size_t)b * 16 + h) * 64 + d) << 10) + s] = f2bf(c);
          }
        }
      }
}

// ---------- attention: swapped-operand QK/PV, XOR-swizzled LDS ----------
// Frozen at the R6/R8 version (<=52 us). V-direct (R15) regressed: the
// compiler sinks plain V loads to the PV loop (VGPR 84), exposing L2
// latency; LDS staging's ds_write is the hard consumption point that
// forces loads a full chunk early.
__global__ __launch_bounds__(256, 2)
void attn_kernel(const uint16_t* __restrict__ qb, const uint16_t* __restrict__ kb,
                 const uint16_t* __restrict__ vtb, const uint32_t* __restrict__ bits,
                 uint16_t* __restrict__ attn_out, float* __restrict__ rlout) {
  __shared__ __align__(16) uint16_t Ks[128 * 64];    // [s][d] swizzled, 16 KB
  __shared__ __align__(16) uint16_t Vs[64 * 128];    // [d][s] swizzled, 16 KB
  __shared__ __align__(16) uint16_t Pb[4 * 32 * 128];// per-wave [t32][s128], 32 KB

  const int bid = blockIdx.x;              // 512 blocks
  const int xcd = bid & 7, j = bid >> 3;   // round-robin dispatch -> XCD
  const int slab = xcd * 8 + (j >> 3);     // 8 (b,h) slabs per XCD
  const int b = slab >> 4, h = slab & 15;
  const int t0 = (j & 7) << 7;             // 128 t-rows per block
  const int tid = threadIdx.x, wave = tid >> 6, lane = tid & 63;
  const int quad = lane >> 4, l16 = lane & 15;
  const int sw = (l16 & 7) << 4;           // XOR swizzle for row=l16 reads
  const size_t bh = (size_t)b * 16 + h;
  const int tw = t0 + wave * 32;
  const int ta = tw + l16, tb = ta + 16;   // lane's two t rows
  char* PwA = (char*)(Pb + wave * (32 * 128)) + l16 * 256;
  char* PwB = PwA + 16 * 256;

  // Q B-frags (op1: col=t=l16), rows ta / tb
  const uint16_t* qA = qb + ((bh << 10) + ta) * 64;
  bf16x8 aqA0 = *(const bf16x8*)(qA + quad * 8);
  bf16x8 aqA1 = *(const bf16x8*)(qA + 32 + quad * 8);
  bf16x8 aqB0 = *(const bf16x8*)(qA + 1024 + quad * 8);
  bf16x8 aqB1 = *(const bf16x8*)(qA + 1024 + 32 + quad * 8);

  f32x4 accA[4] = {}, accB[4] = {};
  float smA = 0.f, smB = 0.f;

  const int kr = tid >> 3, kc8 = tid & 7;    // K staging: 32 rows/round
  const int vr = tid >> 4, vc16 = tid & 15;  // V staging: 16 rows/round

  const uint32_t* bA = bits + (((size_t)(b << 10) + ta) << 5);
  const uint32_t* bB = bits + (((size_t)(b << 10) + tb) << 5);

  // prologue: coalesced loads of chunk 0 + its mask words
  u16x8 kreg[4], vreg[4];
#pragma unroll
  for (int r = 0; r < 4; r++)
    kreg[r] = *(const u16x8*)(kb + (bh << 16) + (size_t)(r * 256 + tid) * 8);
#pragma unroll
  for (int r = 0; r < 4; r++)
    vreg[r] = *(const u16x8*)(vtb + (((bh << 6) + r * 16 + vr) << 10) + vc16 * 8);
  uint4 uA = *(const uint4*)bA;
  uint4 uB = *(const uint4*)bB;

  for (int sc = 0; sc < 8; sc++) {
    // pre-shifted mask words for this chunk (from prefetched uA/uB)
    uint32_t wA[4] = {uA.x >> (quad * 4), uA.y >> (quad * 4),
                      uA.z >> (quad * 4), uA.w >> (quad * 4)};
    uint32_t wB[4] = {uB.x >> (quad * 4), uB.y >> (quad * 4),
                      uB.z >> (quad * 4), uB.w >> (quad * 4)};

    __syncthreads();  // prior chunk's LDS reads done; staging loads drained
#pragma unroll
    for (int r = 0; r < 4; r++) {
      const int row = r * 32 + kr;
      *(u16x8*)((char*)Ks + row * 128 + ((kc8 * 16) ^ ((row & 7) << 4))) = kreg[r];
    }
#pragma unroll
    for (int r = 0; r < 4; r++) {
      const int row = r * 16 + vr;
      *(u16x8*)((char*)Vs + row * 256 + ((vc16 * 16) ^ ((row & 7) << 4))) = vreg[r];
    }
    __syncthreads();  // staging visible

    if (sc < 7) {  // T14: issue next chunk's loads; latency hides under compute
      const uint16_t* kbase = kb + (bh << 16) + (size_t)(sc + 1) * 8192;
#pragma unroll
      for (int r = 0; r < 4; r++)
        kreg[r] = *(const u16x8*)(kbase + (size_t)(r * 256 + tid) * 8);
#pragma unroll
      for (int r = 0; r < 4; r++)
        vreg[r] = *(const u16x8*)(vtb + (((bh << 6) + r * 16 + vr) << 10) +
                                  (sc + 1) * 128 + vc16 * 8);
      uA = *(const uint4*)(bA + (sc + 1) * 4);
      uB = *(const uint4*)(bB + (sc + 1) * 4);
    }

    // QK^T (swapped: D[s=quad*4+r][t=l16]) + streamed exp -> packed P rows
#pragma unroll
    for (int nn = 0; nn < 8; nn++) {
      const char* kbp = (const char*)Ks + (nn * 16 + l16) * 128;
      bf16x8 bk0 = *(const bf16x8*)(kbp + ((quad * 16) ^ sw));
      bf16x8 bk1 = *(const bf16x8*)(kbp + ((64 + quad * 16) ^ sw));
      f32x4 cA = {}, cB = {};
      cA = mfma16(bk0, aqA0, cA); cA = mfma16(bk1, aqA1, cA);
      cB = mfma16(bk0, aqB0, cB); cB = mfma16(bk1, aqB1, cB);
      const uint32_t mA = wA[nn >> 1] >> ((nn & 1) * 16);
      const uint32_t mB = wB[nn >> 1] >> ((nn & 1) * 16);
      float eA[4], eB[4];
#pragma unroll
      for (int r = 0; r < 4; r++) {
        eA[r] = __expf(cA[r]); smA += eA[r];
        eB[r] = __expf(cB[r]); smB += eB[r];
        eA[r] = ((mA >> r) & 1) ? eA[r] : 0.f;  // mask AFTER rowsum (softmax*hard)
        eB[r] = ((mB >> r) & 1) ? eB[r] : 0.f;
      }
      const int pc = (nn * 32 + quad * 8) ^ sw;
      *(uint2*)(PwA + pc) = make_uint2(cvtpk(eA[0], eA[1]), cvtpk(eA[2], eA[3]));
      *(uint2*)(PwB + pc) = make_uint2(cvtpk(eB[0], eB[1]), cvtpk(eB[2], eB[3]));
    }

    // PV (swapped: D[d=quad*4+r][t=l16]); P wave-private -> no barrier
#pragma unroll
    for (int kc = 0; kc < 4; kc++) {
      const int pcb = (kc * 64 + quad * 16) ^ sw;
      bf16x8 apA = *(const bf16x8*)(PwA + pcb);
      bf16x8 apB = *(const bf16x8*)(PwB + pcb);
#pragma unroll
      for (int dt = 0; dt < 4; dt++) {
        bf16x8 bv = *(const bf16x8*)((const char*)Vs + (dt * 16 + l16) * 256 +
                                     ((kc * 64 + quad * 16) ^ sw));
        accA[dt] = mfma16(bv, apA, accA[dt]);
        accB[dt] = mfma16(bv, apB, accB[dt]);
      }
    }
  }

  // row-sums: t is lane-local; reduce across quads only
  smA += __shfl_xor(smA, 16); smA += __shfl_xor(smA, 32);
  smB += __shfl_xor(smB, 16); smB += __shfl_xor(smB, 32);
  const float rlA = 1.0f / smA, rlB = 1.0f / smB;
  if (quad == 0) rlout[(bh << 10) + ta] = rlA;
  if (quad == 1) rlout[(bh << 10) + tb] = rlB;

  // O epilogue: 4 consecutive d per lane -> packed 8B stores
#pragma unroll
  for (int dt = 0; dt < 4; dt++) {
    uint2 oA = make_uint2(cvtpk(accA[dt][0] * rlA, accA[dt][1] * rlA),
                          cvtpk(accA[dt][2] * rlA, accA[dt][3] * rlA));
    *(uint2*)(attn_out + ((size_t)(ta * 4 + b) << 10) + h * 64 + dt * 16 + quad * 4) = oA;
    uint2 oB = make_uint2(cvtpk(accB[dt][0] * rlB, accB[dt][1] * rlB),
                          cvtpk(accB[dt][2] * rlB, accB[dt][3] * rlB));
    *(uint2*)(attn_out + ((size_t)(tb * 4 + b) << 10) + h * 64 + dt * 16 + quad * 4) = oB;
  }
}

// ---------- tail: fused avg (blocks 0..511) + out-projection (512..1023) ----
// Frozen at the R6 version (227.0 us total, session best). 2-head avg
// staging (R15) regressed ~16 us: doubled register-held prefetch + doubled
// ds_write burst, while barrier count was not the critical path.
__global__ __launch_bounds__(256, 4)
void tail(const uint16_t* __restrict__ qb, const uint16_t* __restrict__ kb,
          const float* __restrict__ rlin, const float* __restrict__ hard,
          const uint16_t* __restrict__ Ao, const uint16_t* __restrict__ Bw,
          const float* __restrict__ opb,
          float* __restrict__ out, float* __restrict__ avgout) {
  __shared__ __align__(16) char smem[16384];
  const int bid = blockIdx.x;
  const int tid = threadIdx.x, wave = tid >> 6, lane = tid & 63;
  const int quad = lane >> 4, l16 = lane & 15;

  if (bid < 512) {
    // ---- avg path: swapped-operand QK, swizzled K, float4 stores ----
    uint16_t* Ks = (uint16_t*)smem;          // 16 KB swizzled K-tile
    const int xcd = bid & 7, j = bid >> 3;
    const int b  = xcd >> 1;
    const int t0 = ((xcd & 1) * 8 + (j >> 3)) << 6;
    const int s0 = (j & 7) << 7;
    const int sw = (l16 & 7) << 4;
    const int tr = t0 + wave * 16 + l16;     // lane's t row
    const int kr = tid >> 3, kc8 = tid & 7;

    float av[8][4] = {};

    u16x8 kreg[4];
    {
      const uint16_t* kb0 = kb + ((((size_t)b * 16) << 10) + s0) * 64;
#pragma unroll
      for (int r = 0; r < 4; r++)
        kreg[r] = *(const u16x8*)(kb0 + (size_t)(r * 256 + tid) * 8);
    }

    for (int hh = 0; hh < 16; hh++) {
      __syncthreads();
#pragma unroll
      for (int r = 0; r < 4; r++) {
        const int row = r * 32 + kr;
        *(u16x8*)((char*)Ks + row * 128 + ((kc8 * 16) ^ ((row & 7) << 4))) = kreg[r];
      }
      __syncthreads();
      if (hh < 15) {  // prefetch next head's K-tile under compute
        const uint16_t* kb2 = kb + ((((size_t)b * 16 + hh + 1) << 10) + s0) * 64;
#pragma unroll
        for (int r = 0; r < 4; r++)
          kreg[r] = *(const u16x8*)(kb2 + (size_t)(r * 256 + tid) * 8);
      }

      const size_t bh = (size_t)b * 16 + hh;
      const uint16_t* qrow = qb + ((bh << 10) + tr) * 64;
      bf16x8 aq0 = *(const bf16x8*)(qrow + quad * 8);
      bf16x8 aq1 = *(const bf16x8*)(qrow + 32 + quad * 8);
      const float rl = rlin[(bh << 10) + tr];

#pragma unroll
      for (int n = 0; n < 8; n++) {
        const char* kbp = (const char*)Ks + (n * 16 + l16) * 128;
        bf16x8 bk0 = *(const bf16x8*)(kbp + ((quad * 16) ^ sw));
        bf16x8 bk1 = *(const bf16x8*)(kbp + ((64 + quad * 16) ^ sw));
        f32x4 c = {};
        c = mfma16(bk0, aq0, c);
        c = mfma16(bk1, aq1, c);
#pragma unroll
        for (int r = 0; r < 4; r++) av[n][r] += __expf(c[r]) * rl;
      }
    }

    // mask directly from immutable hard input (fp32 {0,1}), float4 per n
    const float* hrow = hard + (((size_t)(b << 10) + tr) << 10) + s0 + quad * 4;
    float* orow = avgout + ((size_t)(b << 10) + tr) * 1024 + s0 + quad * 4;
#pragma unroll
    for (int n = 0; n < 8; n++) {
      float4 hm = *(const float4*)(hrow + n * 16);
      float4 f;
      f.x = av[n][0] * (hm.x != 0.f ? 0.0625f : 0.f);
      f.y = av[n][1] * (hm.y != 0.f ? 0.0625f : 0.f);
      f.z = av[n][2] * (hm.z != 0.f ? 0.0625f : 0.f);
      f.w = av[n][3] * (hm.w != 0.f ? 0.0625f : 0.f);
      *(float4*)(orow + n * 16) = f;
    }
  } else {
    // ---- out-projection path: 64x128 tiles, XCD swizzle (512 = 8*64) ----
    uint16_t* As = (uint16_t*)smem;            // 4 KB
    uint16_t* Bs = (uint16_t*)(smem + 4096);   // 8 KB
    const int u = bid - 512;
    const int swz = (u & 7) * 64 + (u >> 3);   // same-bm blocks on one XCD
    const int bm = swz >> 3, bn = swz & 7;
    const int wm = (wave >> 1) << 5, wn = (wave & 1) << 6;
    const int K = 1024;

    f32x4 acc[2][4] = {};

    for (int k0 = 0; k0 < K; k0 += 32) {
      __syncthreads();
      {
        int c   = wave * 64 + lane;
        int row = c >> 2, kc = c & 3;
        const uint16_t* ga = Ao + (size_t)(bm * 64 + row) * K + k0 + kc * 8;
        GLD_TO_LDS16(ga, As + (size_t)(wave * 64) * 8);
      }
#pragma unroll
      for (int jj = 0; jj < 2; jj++) {
        int c   = wave * 128 + jj * 64 + lane;
        int row = c >> 2, kc = c & 3;
        const uint16_t* gb = Bw + (size_t)(bn * 128 + row) * K + k0 + kc * 8;
        GLD_TO_LDS16(gb, Bs + (size_t)(wave * 128 + jj * 64) * 8);
      }
      __syncthreads();

      bf16x8 af[2], bfr[4];
#pragma unroll
      for (int i = 0; i < 2; i++)
        af[i] = *(const bf16x8*)(As + (wm + i * 16 + l16) * 32 + quad * 8);
#pragma unroll
      for (int i = 0; i < 4; i++)
        bfr[i] = *(const bf16x8*)(Bs + (wn + i * 16 + l16) * 32 + quad * 8);
#pragma unroll
      for (int mi = 0; mi < 2; mi++)
#pragma unroll
        for (int ni = 0; ni < 4; ni++)
          acc[mi][ni] = mfma16(af[mi], bfr[ni], acc[mi][ni]);
    }

#pragma unroll
    for (int mi = 0; mi < 2; mi++)
#pragma unroll
      for (int ni = 0; ni < 4; ni++)
#pragma unroll
        for (int r = 0; r < 4; r++) {
          int gi = bm * 64 + wm + mi * 16 + quad * 4 + r;
          int gf = bn * 128 + wn + ni * 16 + l16;
          out[(size_t)gi * 1024 + gf] = acc[mi][ni][r] + opb[gf];
        }
  }
}

// ---------- launch ----------
extern "C" void kernel_launch(void* const* d_in, const int* in_sizes, int n_in,
                              void* d_out, int out_size, void* d_ws, size_t ws_size,
                              hipStream_t stream) {
  const float* query = (const float*)d_in[0];
  const float* key   = (const float*)d_in[1];
  const float* hard  = (const float*)d_in[2];
  const float* ipw   = (const float*)d_in[3];
  const float* ipb   = (const float*)d_in[4];
  const float* opw   = (const float*)d_in[5];
  const float* opb   = (const float*)d_in[6];

  char* ws = (char*)d_ws;
  const size_t MB = 1ull << 20;
  uint16_t* Xq  = (uint16_t*)(ws + 0);        // 8 MB (reused as attn_out)
  uint16_t* Xk  = (uint16_t*)(ws + 8 * MB);   // 8 MB (reused as rl buffer)
  uint16_t* Wb  = (uint16_t*)(ws + 16 * MB);  // 6 MB
  uint16_t* Wob = (uint16_t*)(ws + 22 * MB);  // 2 MB
  uint16_t* Qb  = (uint16_t*)(ws + 24 * MB);  // 8 MB (b,h,t,d)
  uint16_t* Kb  = (uint16_t*)(ws + 32 * MB);  // 8 MB (b,h,s,d)
  uint16_t* Vt  = (uint16_t*)(ws + 40 * MB);  // 8 MB (b,h,d,s)
  uint16_t* AO  = Xq;                         // alias: Xq dead after gemm_qkv
  float*    rlws = (float*)(ws + 8 * MB);     // alias: Xk dead after gemm_qkv

  float* out = (float*)d_out;
  float* avg = out + 4194304;
  // bits (512 KB) parked in the out region: only read by attn, which
  // completes before tail's gemm_out path overwrites it.
  uint32_t* bits = (uint32_t*)out;

  // fused cast (12288 blocks) + bitpack (4096 blocks, 4x vectorized)
  prep<<<16384, 256, 0, stream>>>(query, key, ipw, opw, hard,
                                  Xq, Xk, Wb, Wob, bits);

  // fused Q-proj (256) + KV-proj (512), 128^2 BK=64 2-phase + swizzles
  gemm_qkv<<<768, 256, 0, stream>>>(Xq, Xk, Wb, ipb, Qb, Kb, Vt);

  // attention (K+V staged, swizzled, 2 blocks/CU): AO + 1/rowsum
  attn_kernel<<<512, 256, 0, stream>>>(Qb, Kb, Vt, bits, AO, rlws);

  // fused head-averaged attention map + out-projection
  tail<<<1024, 256, 0, stream>>>(Qb, Kb, rlws, hard, AO, Wob, opb, out, avg);
}